// Round 5
// baseline (244.259 us; speedup 1.0000x reference)
//
#include <hip/hip_runtime.h>

#define N_TERMS 2048
#define NCOL 4096
#define NC4 1024                           // float4 per row
#define NCHUNK 128
#define RPC (N_TERMS / NCHUNK)             // 16 rows per chunk

typedef float f4_t __attribute__((ext_vector_type(4)));

// ---------------------------------------------------------------------------
// Kernel 1: pure x-read -> partial column |x| sums (bitwise-identical mapping
// to the verified round-0 kernel). Also zeroes the two sync counters used by
// kernel 2 (zeroed in the PREVIOUS kernel -> no init race; ws is poisoned).
// ---------------------------------------------------------------------------
__global__ void k_partial_abs(const float* __restrict__ x, float* __restrict__ partial,
                              int* __restrict__ ctrs) {
    if (blockIdx.x == 0 && blockIdx.y == 0 && threadIdx.x == 0) {
        ctrs[0] = 0;  // zdone
        ctrs[1] = 0;  // sdone
    }
    int col4 = blockIdx.x * blockDim.x + threadIdx.x;  // [0, 1024)
    int chunk = blockIdx.y;
    int r0 = chunk * RPC;
    int r1 = r0 + RPC;
    if (r0 == 0) r0 = 1;  // center row excluded from abs_sum
    const f4_t* x4 = (const f4_t*)x;
    f4_t acc = {0.f, 0.f, 0.f, 0.f};
#pragma unroll
    for (int r = r0; r < r1; ++r) {
        f4_t v = x4[(long)r * NC4 + col4];
        acc.x += fabsf(v.x);
        acc.y += fabsf(v.y);
        acc.z += fabsf(v.z);
        acc.w += fabsf(v.w);
    }
    ((f4_t*)partial)[chunk * NC4 + col4] = acc;
}

// ---------------------------------------------------------------------------
// Kernel 2: everything else, one dispatch, 1601 blocks.
//   b 0..511    : zero the 67 MB tail region, then release zdone.
//   b 512..575  : verified per-column stats (partial is visible via the
//                 kernel boundary; math/order bitwise-identical), release sdone.
//   b 576..1599 : gens rows 1..2047 (x * scale): spin ~3 us on sdone==64,
//                 then stream 33.5 MB of L3-resident x -> 33.5 MB of writes,
//                 SHARING the write pipe with the tail zeros instead of
//                 serializing behind them at a dispatch boundary.
//   b 1600      : prefix scan + scatter of ~2048 dhalf values into the zeroed
//                 tail; spins on zdone==512 && sdone==64.
// Deadlock safety: 1601 blocks x 256 thr, 2 KB LDS, ~32 VGPR -> 8 blocks/CU
// x 256 CU = 2048 resident slots > 1601, so ALL blocks are co-resident
// regardless of dispatch order; spin-waits cannot starve their producers.
// Visibility: producers __syncthreads() (drains vmcnt) + __threadfence() +
// device-scope atomicAdd release; consumers agent-scope atomic spin +
// __threadfence() acquire (invalidates CU L1).
// ---------------------------------------------------------------------------
__global__ __launch_bounds__(256) void k_main(
    const float* __restrict__ x, const float* __restrict__ partial,
    float* __restrict__ out, float* __restrict__ scale,
    float* __restrict__ dhalf, int* __restrict__ crossflag,
    int* __restrict__ ctrs) {
    const int b = blockIdx.x;
    const int t = threadIdx.x;
    int* zdone = ctrs + 0;
    int* sdone = ctrs + 1;

    __shared__ float red[4][64];
    __shared__ int tsum[256];

    if (b < 512) {
        // ---- tail zero: 512 blocks x 256 thr x 32 f4 = 67.1 MB ------------
        f4_t* o4 = (f4_t*)out;
        const long base4 = (long)N_TERMS * NC4 + (long)b * 8192;
        const f4_t z = {0.f, 0.f, 0.f, 0.f};
#pragma unroll
        for (int i = 0; i < 32; ++i)
            __builtin_nontemporal_store(z, &o4[base4 + i * 256 + t]);
        __syncthreads();  // drains vmcnt(0): all NT stores issued to fabric
        if (t == 0) {
            __threadfence();
            atomicAdd(zdone, 1);
        }
    } else if (b < 576) {
        // ---- stats: verified math/order (absmax must stay 0.0) ------------
        const int sb = b - 512;
        const int lane = t & 63;
        const int q = t >> 6;
        const int c = sb * 64 + lane;

        float s0 = 0.f, s1 = 0.f, s2 = 0.f, s3 = 0.f;
        const int k0 = q * 32;
#pragma unroll 8
        for (int k = 0; k < 32; k += 4) {
            s0 += partial[(k0 + k + 0) * NCOL + c];
            s1 += partial[(k0 + k + 1) * NCOL + c];
            s2 += partial[(k0 + k + 2) * NCOL + c];
            s3 += partial[(k0 + k + 3) * NCOL + c];
        }
        red[q][lane] = (s0 + s1) + (s2 + s3);
        __syncthreads();
        if (q == 0) {
            float s = (red[0][lane] + red[1][lane]) + (red[2][lane] + red[3][lane]);
            float x0 = x[c];
            float u = x0 + s;
            float l = x0 - s;
            bool cross = (l * u) < 0.0f;
            bool pos = (l >= 0.0f);
            float denom = u - l;
            float lam = (pos ? 1.0f : 0.0f) +
                        (cross ? ((denom != 0.0f) ? u / denom : 0.5f) : 0.0f);
            float delta = fmaxf(-lam * l, (1.0f - lam) * u);
            float crossf = cross ? 1.0f : 0.0f;
            float posf = pos ? 1.0f : 0.0f;
            out[c] = (delta * 0.5f + lam * x0) * crossf + x0 * posf;  // row 0
            scale[c] = lam * crossf + posf;
            dhalf[c] = delta * 0.5f * crossf;
            crossflag[c] = cross ? 1 : 0;
        }
        __syncthreads();  // all stores of the block issued
        if (t == 0) {
            __threadfence();
            atomicAdd(sdone, 1);
        }
    } else if (b < 1600) {
        // ---- gens: spin on scale ready, then stream ----------------------
        if (t == 0) {
            while (__hip_atomic_load(sdone, __ATOMIC_RELAXED,
                                     __HIP_MEMORY_SCOPE_AGENT) < 64)
                __builtin_amdgcn_s_sleep(8);
        }
        __syncthreads();
        __threadfence();  // acquire: invalidate L1, see stats' stores

        const int gb = b - 576;            // [0, 1024)
        const int g = gb * 256 + t;        // [0, 262144)
        const int col4 = g & 1023;
        const int group0 = g >> 10;        // [0, 256)
        const f4_t* x4 = (const f4_t*)x;
        f4_t* o4 = (f4_t*)out;
        const f4_t sc = ((const f4_t*)scale)[col4];
#pragma unroll
        for (int h = 0; h < 2; ++h) {
            const int group = group0 + h * 256;  // [0, 512)
            const int r0 = group << 2;
            if (group == 0) {
#pragma unroll
                for (int r = 1; r < 4; ++r) {
                    f4_t v = x4[(long)r * NC4 + col4] * sc;
                    __builtin_nontemporal_store(v, &o4[(long)r * NC4 + col4]);
                }
            } else {
#pragma unroll
                for (int i = 0; i < 4; ++i) {
                    const int r = r0 + i;
                    f4_t v = x4[(long)r * NC4 + col4] * sc;
                    __builtin_nontemporal_store(v, &o4[(long)r * NC4 + col4]);
                }
            }
        }
    } else {
        // ---- scatter: spin on tail zeroed + stats ready ------------------
        if (t == 0) {
            while (__hip_atomic_load(zdone, __ATOMIC_RELAXED,
                                     __HIP_MEMORY_SCOPE_AGENT) < 512 ||
                   __hip_atomic_load(sdone, __ATOMIC_RELAXED,
                                     __HIP_MEMORY_SCOPE_AGENT) < 64)
                __builtin_amdgcn_s_sleep(8);
        }
        __syncthreads();
        __threadfence();  // acquire

        const int T = 256;
        const int PER = NCOL / T;  // 16
        const int base = t * PER;
        int cf[PER];
        int ex[PER];
        int run = 0;
#pragma unroll
        for (int i = 0; i < PER; ++i) {
            cf[i] = crossflag[base + i];
            ex[i] = run;
            run += cf[i];
        }
        tsum[t] = run;
        __syncthreads();
        for (int off = 1; off < T; off <<= 1) {
            int v = 0;
            if (t >= off) v = tsum[t - off];
            __syncthreads();
            tsum[t] += v;
            __syncthreads();
        }
        const int excl = (t == 0) ? 0 : tsum[t - 1];
#pragma unroll
        for (int i = 0; i < PER; ++i) {
            if (cf[i]) {
                const int c = base + i;
                const long row = N_TERMS + excl + ex[i];
                out[row * (long)NCOL + c] = dhalf[c];  // tail already zeroed
            }
        }
    }
}

extern "C" void kernel_launch(void* const* d_in, const int* in_sizes, int n_in,
                              void* d_out, int out_size, void* d_ws, size_t ws_size,
                              hipStream_t stream) {
    const float* x = (const float*)d_in[0];
    float* out = (float*)d_out;

    float* ws = (float*)d_ws;
    float* partial   = ws;                       // 128*4096 floats = 2 MB
    float* scale     = partial + NCHUNK * NCOL;  // 4096 floats
    float* dhalf     = scale + NCOL;             // 4096 floats
    int*   crossflag = (int*)(dhalf + NCOL);     // 4096 ints
    int*   ctrs      = crossflag + NCOL;         // 2 ints (zdone, sdone)

    k_partial_abs<<<dim3(NC4 / 256, NCHUNK), 256, 0, stream>>>(x, partial, ctrs);
    k_main<<<1601, 256, 0, stream>>>(x, partial, out, scale, dhalf, crossflag, ctrs);
}

// Round 6
// 137.701 us; speedup vs baseline: 1.7738x; 1.7738x over previous
//
#include <hip/hip_runtime.h>

#define N_TERMS 2048
#define NCOL 4096
#define NC4 1024                           // float4 per row
#define NCHUNK 128
#define RPC (N_TERMS / NCHUNK)             // 16 rows per chunk

typedef float f4_t __attribute__((ext_vector_type(4)));

// ---------------------------------------------------------------------------
// VERIFIED BEST (round 4: 137.1 us, absmax 0.0). Round 5's intra-kernel
// producer/consumer merge regressed to 244 us (spin-observation latency across
// XCDs); round 1's cooperative version regressed to 319 us. Dependencies must
// cross kernel boundaries on this chip. Schedule rationale:
//   K1: pure x-read (critical path: gates stats -> scale -> gens). Runs alone.
//   K2: 67 MB tail-zero stream, with the latency-bound stats blocks hidden
//       under it (block-partitioned, no sync needed within the dispatch).
//   K3: gens write stream, with the prefix-scan + ~2048-element dhalf scatter
//       hidden under it as one extra block (scatter targets are pre-zeroed).
// ---------------------------------------------------------------------------

// Kernel 1: partial column |x| sums (bitwise-identical mapping to the
// verified baseline reduction order).
__global__ void k_partial_abs(const float* __restrict__ x, float* __restrict__ partial) {
    int col4 = blockIdx.x * blockDim.x + threadIdx.x;  // [0, 1024)
    int chunk = blockIdx.y;
    int r0 = chunk * RPC;
    int r1 = r0 + RPC;
    if (r0 == 0) r0 = 1;  // center row excluded from abs_sum
    const f4_t* x4 = (const f4_t*)x;
    f4_t acc = {0.f, 0.f, 0.f, 0.f};
#pragma unroll
    for (int r = r0; r < r1; ++r) {
        f4_t v = x4[(long)r * NC4 + col4];
        acc.x += fabsf(v.x);
        acc.y += fabsf(v.y);
        acc.z += fabsf(v.z);
        acc.w += fabsf(v.w);
    }
    ((f4_t*)partial)[chunk * NC4 + col4] = acc;
}

// Kernel 2 (block-partitioned): blocks 0..63 per-column stats (verified
// math/order); blocks 64..575 zero the 67 MB tail. Stats latency hides under
// the zero-write stream.
__global__ void k_stats_zero(const float* __restrict__ x, const float* __restrict__ partial,
                             float* __restrict__ out, float* __restrict__ scale,
                             float* __restrict__ dhalf, int* __restrict__ crossflag) {
    const int b = blockIdx.x;
    const int t = threadIdx.x;

    if (b < 64) {
        const int lane = t & 63;        // column within block's 64-col slice
        const int q = t >> 6;           // which quarter of the 128 chunks
        const int c = b * 64 + lane;

        float s0 = 0.f, s1 = 0.f, s2 = 0.f, s3 = 0.f;
        const int k0 = q * 32;
#pragma unroll 8
        for (int k = 0; k < 32; k += 4) {
            s0 += partial[(k0 + k + 0) * NCOL + c];
            s1 += partial[(k0 + k + 1) * NCOL + c];
            s2 += partial[(k0 + k + 2) * NCOL + c];
            s3 += partial[(k0 + k + 3) * NCOL + c];
        }
        __shared__ float red[4][64];
        red[q][lane] = (s0 + s1) + (s2 + s3);
        __syncthreads();
        if (q == 0) {
            float s = (red[0][lane] + red[1][lane]) + (red[2][lane] + red[3][lane]);
            float x0 = x[c];
            float u = x0 + s;
            float l = x0 - s;
            bool cross = (l * u) < 0.0f;
            bool pos = (l >= 0.0f);
            float denom = u - l;
            float lam = (pos ? 1.0f : 0.0f) +
                        (cross ? ((denom != 0.0f) ? u / denom : 0.5f) : 0.0f);
            float delta = fmaxf(-lam * l, (1.0f - lam) * u);
            float crossf = cross ? 1.0f : 0.0f;
            float posf = pos ? 1.0f : 0.0f;
            out[c] = (delta * 0.5f + lam * x0) * crossf + x0 * posf;  // output row 0
            scale[c] = lam * crossf + posf;
            dhalf[c] = delta * 0.5f * crossf;
            crossflag[c] = cross ? 1 : 0;
        }
    } else {
        // zero tail rows 2048..6143: 512 blocks x 256 thr x 32 f4 = 67.1 MB
        const int zb = b - 64;                 // [0, 512)
        f4_t* o4 = (f4_t*)out;
        const long base4 = (long)N_TERMS * NC4 + (long)zb * 8192;
        const f4_t z = {0.f, 0.f, 0.f, 0.f};
#pragma unroll
        for (int i = 0; i < 32; ++i)
            __builtin_nontemporal_store(z, &o4[base4 + i * 256 + t]);
    }
}

// Kernel 3: gens rows 1..2047 (x * scale[col]; x is L3-resident) on blocks
// 0..2047, plus ONE extra block doing the 4096-wide prefix scan and the
// ~2048-element dhalf scatter into the pre-zeroed tail.
__global__ void k_gens_scatter(const float* __restrict__ x, const float* __restrict__ scale,
                               const float* __restrict__ dhalf,
                               const int* __restrict__ crossflag,
                               float* __restrict__ out) {
    const int b = blockIdx.x;
    const int t = threadIdx.x;
    if (b < 2048) {
        const int g = b * 256 + t;        // [0, 524288)
        const int col4 = g & 1023;
        const int group = g >> 10;        // [0, 512)
        const int r0 = group << 2;
        const f4_t* x4 = (const f4_t*)x;
        f4_t* o4 = (f4_t*)out;
        const f4_t sc = ((const f4_t*)scale)[col4];

        if (group == 0) {
#pragma unroll
            for (int r = 1; r < 4; ++r) {
                f4_t v = x4[(long)r * NC4 + col4] * sc;
                __builtin_nontemporal_store(v, &o4[(long)r * NC4 + col4]);
            }
        } else {
#pragma unroll
            for (int i = 0; i < 4; ++i) {
                const int r = r0 + i;
                f4_t v = x4[(long)r * NC4 + col4] * sc;
                __builtin_nontemporal_store(v, &o4[(long)r * NC4 + col4]);
            }
        }
    } else {
        // exclusive prefix sum of crossflag + direct scatter (integer-exact)
        const int T = 256;
        const int PER = NCOL / T;  // 16
        __shared__ int tsum[T];
        const int base = t * PER;
        int cf[PER];
        int ex[PER];
        int run = 0;
#pragma unroll
        for (int i = 0; i < PER; ++i) {
            cf[i] = crossflag[base + i];
            ex[i] = run;
            run += cf[i];
        }
        tsum[t] = run;
        __syncthreads();
        for (int off = 1; off < T; off <<= 1) {
            int v = 0;
            if (t >= off) v = tsum[t - off];
            __syncthreads();
            tsum[t] += v;
            __syncthreads();
        }
        const int excl = (t == 0) ? 0 : tsum[t - 1];
#pragma unroll
        for (int i = 0; i < PER; ++i) {
            if (cf[i]) {
                const int c = base + i;
                const long row = N_TERMS + excl + ex[i];
                out[row * (long)NCOL + c] = dhalf[c];  // tail zeroed by k_stats_zero
            }
        }
    }
}

extern "C" void kernel_launch(void* const* d_in, const int* in_sizes, int n_in,
                              void* d_out, int out_size, void* d_ws, size_t ws_size,
                              hipStream_t stream) {
    const float* x = (const float*)d_in[0];
    float* out = (float*)d_out;

    float* ws = (float*)d_ws;
    float* partial   = ws;                       // 128*4096 floats = 2 MB
    float* scale     = partial + NCHUNK * NCOL;  // 4096 floats
    float* dhalf     = scale + NCOL;             // 4096 floats
    int*   crossflag = (int*)(dhalf + NCOL);     // 4096 ints

    k_partial_abs<<<dim3(NC4 / 256, NCHUNK), 256, 0, stream>>>(x, partial);
    k_stats_zero<<<576, 256, 0, stream>>>(x, partial, out, scale, dhalf, crossflag);
    k_gens_scatter<<<2049, 256, 0, stream>>>(x, scale, dhalf, crossflag, out);
}